// Round 5
// baseline (279.445 us; speedup 1.0000x reference)
//
#include <hip/hip_runtime.h>
#include <stdint.h>

typedef unsigned short u16;
typedef __bf16 bf16x8 __attribute__((ext_vector_type(8)));
typedef float f32x4 __attribute__((ext_vector_type(4)));

__device__ __forceinline__ u16 f2bf(float f) {
  union { float f; uint32_t u; } x; x.f = f;
  uint32_t u = x.u;
  u += 0x7fffu + ((u >> 16) & 1u);   // round-to-nearest-even
  return (u16)(u >> 16);
}
__device__ __forceinline__ float bf2f(uint32_t lo16) {
  union { uint32_t u; float f; } x; x.u = lo16 << 16; return x.f;
}

__device__ __forceinline__ void async_load16(const u16* g, u16* l) {
  __builtin_amdgcn_global_load_lds(
      (const __attribute__((address_space(1))) void*)g,
      (__attribute__((address_space(3))) void*)l,
      16, 0, 0);
}

// ---------------- prep_all: sigmoid(beta) + weight converts + x convert ----------------
__global__ __launch_bounds__(256) void prep_all(const float* __restrict__ x,
                                                const float* __restrict__ Wq,
                                                const float* __restrict__ Wfc,
                                                const float* __restrict__ braw,
                                                u16* __restrict__ xb,
                                                u16* __restrict__ wqb,
                                                u16* __restrict__ wfcb,
                                                float* __restrict__ beta) {
  int gid = blockIdx.x * 256 + threadIdx.x;
  if (gid < 1024) beta[gid] = 1.0f / (1.0f + expf(-braw[gid]));
  if (gid < 131072) {
    const int HH = 1024 * 1024;
    int i = gid * 16;
    const float* src = (i < HH) ? (Wq + i) : (Wfc + (i - HH));
    u16* dst = (i < HH) ? (wqb + i) : (wfcb + (i - HH));
#pragma unroll
    for (int c = 0; c < 4; c++) {
      float4 v = *(const float4*)(src + c * 4);
      ushort4 o = {f2bf(v.x), f2bf(v.y), f2bf(v.z), f2bf(v.w)};
      *(ushort4*)(dst + c * 4) = o;
    }
  }
  {
    int i = gid * 8;
    float4 a = *(const float4*)(x + i);
    float4 b = *(const float4*)(x + i + 4);
    ushort4 o0 = {f2bf(a.x), f2bf(a.y), f2bf(a.z), f2bf(a.w)};
    ushort4 o1 = {f2bf(b.x), f2bf(b.y), f2bf(b.z), f2bf(b.w)};
    *(ushort4*)(xb + i) = o0;
    *(ushort4*)(xb + i + 4) = o1;
  }
}

// ---------------- GEMM: C = A (MxK bf16) * B^T (NxK bf16) + bias ----------------
// 128x128 tile, BK=32, 4 waves (2x2), each wave 64x64 via 4x4 mfma_f32_16x16x32_bf16.
// Proven K-loop (round-2/4 structure, explicit s_waitcnt drain before barrier).
// OUTBF=1 (gemm1): LDS-transposed epilogue -> full-line bf16 q stores (fixes the
// measured 2x WRITE_SIZE inflation from 32B row segments) AND computes per-segment
// scan carries in the same pass (segment = this tile's 16 t-steps), eliminating the
// separate scan_carry kernel + its 32 MB re-read.
template <int RELU, int OUTBF>
__global__ __launch_bounds__(256) void gemm_bt(const u16* __restrict__ A,
                                               const u16* __restrict__ B,
                                               const float* __restrict__ bias,
                                               const float* __restrict__ beta_arr,
                                               float* __restrict__ carry,
                                               void* __restrict__ Cout,
                                               int M, int N, int K) {
  __shared__ u16 As[128 * 32];
  __shared__ u16 Bs[128 * 32];

  const int tid  = threadIdx.x;
  const int lane = tid & 63;

  // XCD-aware remap (grid = 1024 = 128 m-tiles x 8 n-tiles; xcd = L % 8):
  // XCD c owns m-tiles [16c,16c+16) x all 8 n-tiles -> ~3 MB L2 working set.
  const int L  = blockIdx.x;
  const int xc = L & 7;
  const int k8 = L >> 3;
  const int tile_n = (k8 & 7) * 128;
  const int tile_m = ((xc << 4) | (k8 >> 3)) * 128;

  const int wm = ((tid >> 7) & 1) * 64;
  const int wn = ((tid >> 6) & 1) * 64;

  // staging: lane l of wave w covers LDS row w*16 + l/4, 16B chunk l%4.
  // Global source chunk XOR-swizzled so ds_read_b128 quad-groups hit all
  // 8 bank-quads exactly 2x (2-way aliasing = free).
  const int srow = tid >> 2;
  const int scol = (((tid & 3) ^ ((tid >> 3) & 3)) << 3);
  u16* ldsA = &As[(tid >> 6) << 9];
  u16* ldsB = &Bs[(tid >> 6) << 9];

  const u16* gA = A + (size_t)(tile_m + srow) * K + scol;
  const u16* gB = B + (size_t)(tile_n + srow) * K + scol;

  f32x4 acc[4][4];
#pragma unroll
  for (int i = 0; i < 4; i++)
#pragma unroll
    for (int j = 0; j < 4; j++) acc[i][j] = (f32x4){0.f, 0.f, 0.f, 0.f};

  const int lrow = lane & 15;
  const int gcq  = lane >> 4;
  const int ccL8 = (gcq ^ ((lrow >> 1) & 3)) << 3;

  for (int k0 = 0; k0 < K; k0 += 32) {
    __syncthreads();
    async_load16(gA + k0, ldsA);
    async_load16(gA + 64 * (size_t)K + k0, ldsA + 2048);
    async_load16(gB + k0, ldsB);
    async_load16(gB + 64 * (size_t)K + k0, ldsB + 2048);
    __builtin_amdgcn_s_waitcnt(0);  // explicit drain: LDS-DMA complete before publish
    __syncthreads();

    bf16x8 a[4], b[4];
#pragma unroll
    for (int i = 0; i < 4; i++)
      a[i] = *(const bf16x8*)&As[(wm + i * 16 + lrow) * 32 + ccL8];
#pragma unroll
    for (int j = 0; j < 4; j++)
      b[j] = *(const bf16x8*)&Bs[(wn + j * 16 + lrow) * 32 + ccL8];
#pragma unroll
    for (int i = 0; i < 4; i++)
#pragma unroll
      for (int j = 0; j < 4; j++)
        acc[i][j] = __builtin_amdgcn_mfma_f32_16x16x32_bf16(a[i], b[j], acc[i][j], 0, 0, 0);
  }

  // C/D layout: col = lane&15, row = (lane>>4)*4 + r  [measured m89/m91]
  const int crow = (lane >> 4) << 2;
  const int ccol = lane & 15;

  if (OUTBF) {
    // ---- LDS-transposed epilogue + segment carries (segment s = tile_m/128) ----
    // Tile rows = t*8+b for t in [16s,16s+16), b in [0,8); cols = h-channels.
    // Ct = 128 rows x 64 cols (one col-half at a time), chunk-XOR swizzled:
    // element (row,col) stored at chunk ((col>>3)^(row&7)), offset col&7.
    const int s = tile_m >> 7;
    u16* Ct = As;  // 16 KB reuse
    u16* qout = (u16*)Cout;
#pragma unroll
    for (int half = 0; half < 2; half++) {
      __syncthreads();  // K-loop LDS reads done / previous half's readers done
      if (wn == half * 64) {
#pragma unroll
        for (int i = 0; i < 4; i++)
#pragma unroll
          for (int j = 0; j < 4; j++) {
            const int col = j * 16 + ccol;  // 0..63 within half
            const float bv = bias[tile_n + half * 64 + col];
#pragma unroll
            for (int r = 0; r < 4; r++) {
              const int row = wm + i * 16 + crow + r;
              const int cs = ((((col >> 3) ^ (row & 7)) << 3) | (col & 7));
              float v = acc[i][j][r] + bv;
              if (RELU) v = fmaxf(v, 0.f);
              Ct[row * 64 + cs] = f2bf(v);
            }
          }
      }
      __syncthreads();
      // q store: full-line writes. thread -> row tid>>1, 4 chunks of 16B.
      {
        const int row = tid >> 1;
        const int cb = (tid & 1) << 2;
        u16* qr = qout + (size_t)(tile_m + row) * N + tile_n + half * 64;
#pragma unroll
        for (int k = 0; k < 4; k++) {
          const int ck = (cb + k) ^ (row & 7);
          *(uint4*)&qr[(cb + k) << 3] = *(const uint4*)&Ct[row * 64 + (ck << 3)];
        }
      }
      // segment carries: 512 channels this half (8 b x 64 h), 2 per thread.
      // c = local-scan over the 16 t-steps: c = sum_t beta^(15-t) * q[t] (Horner).
#pragma unroll
      for (int cc = 0; cc < 2; cc++) {
        const int c = tid + cc * 256;
        const int b = c >> 6, hcol = c & 63;
        const int h = tile_n + half * 64 + hcol;
        const float bb = beta_arr[h];
        float mloc = 0.f;
#pragma unroll
        for (int t = 0; t < 16; t++) {
          const int cs = ((((hcol >> 3) ^ b) << 3) | (hcol & 7));  // (t*8+b)&7 == b
          mloc = fmaf(bb, mloc, bf2f(Ct[(t * 8 + b) * 64 + cs]));
        }
        carry[(size_t)s * 8192 + b * 1024 + h] = mloc;
      }
    }
  } else {
    // fp32 direct stores (64B row segments — full sectors, measured clean)
#pragma unroll
    for (int i = 0; i < 4; i++) {
#pragma unroll
      for (int j = 0; j < 4; j++) {
        const int gm = tile_m + wm + i * 16 + crow;
        const int gn = tile_n + wn + j * 16 + ccol;
        const float bv = bias[gn];
#pragma unroll
        for (int r = 0; r < 4; r++) {
          float v = acc[i][j][r] + bv;
          if (RELU) v = fmaxf(v, 0.f);
          ((float*)Cout)[(size_t)(gm + r) * N + gn] = v;
        }
      }
    }
  }
}

// ---------------- scan_fuse: inline carry-fold + rescan + emit bf16 m ----------------
// 128 segments of 16 t-steps. Thread (seg, cq): F = Horner-fold of the seg upstream
// carries (4 MB buffer, L2-resident) with ratio beta^16, then rescan its 16 q values
// (4 channels, uint2) from m_{-1}=F and emit bf16 m.
__global__ __launch_bounds__(256) void scan_fuse(const uint2* __restrict__ qb,
                                                 const float4* __restrict__ carry4,
                                                 const float* __restrict__ beta_arr,
                                                 uint2* __restrict__ mb) {
  const int tid = blockIdx.x * 256 + threadIdx.x;  // [0, 128*2048)
  const int seg = tid >> 11;
  const int cq  = tid & 2047;
  const int h0  = (cq * 4) & 1023;
  const float b0 = beta_arr[h0], b1 = beta_arr[h0 + 1];
  const float b2 = beta_arr[h0 + 2], b3 = beta_arr[h0 + 3];
  float s0 = b0, s1 = b1, s2 = b2, s3 = b3;
#pragma unroll
  for (int i = 0; i < 4; i++) { s0 *= s0; s1 *= s1; s2 *= s2; s3 *= s3; }  // beta^16
  float F0 = 0.f, F1 = 0.f, F2 = 0.f, F3 = 0.f;
  const float4* cp = carry4 + cq;
  for (int s = 0; s < seg; s++) {  // uniform per block (seg = tid>>11)
    float4 c = cp[(size_t)s * 2048];
    F0 = fmaf(s0, F0, c.x); F1 = fmaf(s1, F1, c.y);
    F2 = fmaf(s2, F2, c.z); F3 = fmaf(s3, F3, c.w);
  }
  const uint2* p = qb + (size_t)seg * 16 * 2048 + cq;
  uint2* o = mb + (size_t)seg * 16 * 2048 + cq;
  float m0 = F0, m1 = F1, m2 = F2, m3 = F3;
#pragma unroll
  for (int t = 0; t < 16; t++) {
    uint2 v = p[(size_t)t * 2048];
    m0 = fmaf(b0, m0, bf2f(v.x & 0xffffu));
    m1 = fmaf(b1, m1, bf2f(v.x >> 16));
    m2 = fmaf(b2, m2, bf2f(v.y & 0xffffu));
    m3 = fmaf(b3, m3, bf2f(v.y >> 16));
    uint2 w;
    w.x = (uint32_t)f2bf(m0) | ((uint32_t)f2bf(m1) << 16);
    w.y = (uint32_t)f2bf(m2) | ((uint32_t)f2bf(m3) << 16);
    o[(size_t)t * 2048] = w;
  }
}

extern "C" void kernel_launch(void* const* d_in, const int* in_sizes, int n_in,
                              void* d_out, int out_size, void* d_ws, size_t ws_size,
                              hipStream_t stream) {
  const float* x        = (const float*)d_in[0];
  const float* W_q      = (const float*)d_in[1];
  const float* b_q      = (const float*)d_in[2];
  const float* beta_raw = (const float*)d_in[3];
  const float* W_fc     = (const float*)d_in[4];
  const float* b_fc     = (const float*)d_in[5];

  const int H = 1024;
  const int M = 2048 * 8;              // T*B = 16384 rows
  const size_t MH = (size_t)M * H;     // 16.7M elements

  char* ws = (char*)d_ws;
  u16* x_bf    = (u16*)ws;  ws += MH * 2;                   // 32 MB
  u16* q_bf    = (u16*)ws;  ws += MH * 2;                   // 32 MB
  u16* m_bf    = (u16*)ws;  ws += MH * 2;                   // 32 MB
  u16* wq_bf   = (u16*)ws;  ws += (size_t)H * H * 2;        // 2 MB
  u16* wfc_bf  = (u16*)ws;  ws += (size_t)H * H * 2;        // 2 MB
  float* beta  = (float*)ws; ws += 4096;
  float* carry = (float*)ws; ws += (size_t)128 * 8192 * 4;  // 4 MB

  prep_all<<<(int)(MH / 8 / 256), 256, 0, stream>>>(x, W_q, W_fc, beta_raw,
                                                    x_bf, wq_bf, wfc_bf, beta);

  gemm_bt<0, 1><<<1024, 256, 0, stream>>>(x_bf, wq_bf, b_q, beta, carry,
                                          q_bf, M, H, H);

  scan_fuse<<<1024, 256, 0, stream>>>((const uint2*)q_bf, (const float4*)carry,
                                      beta, (uint2*)m_bf);

  gemm_bt<1, 0><<<1024, 256, 0, stream>>>(m_bf, wfc_bf, b_fc, nullptr, nullptr,
                                          d_out, M, H, H);
}

// Round 6
// 251.915 us; speedup vs baseline: 1.1093x; 1.1093x over previous
//
#include <hip/hip_runtime.h>
#include <stdint.h>

typedef unsigned short u16;
typedef __bf16 bf16x8 __attribute__((ext_vector_type(8)));
typedef float f32x4 __attribute__((ext_vector_type(4)));

__device__ __forceinline__ u16 f2bf(float f) {
  union { float f; uint32_t u; } x; x.f = f;
  uint32_t u = x.u;
  u += 0x7fffu + ((u >> 16) & 1u);   // round-to-nearest-even
  return (u16)(u >> 16);
}
__device__ __forceinline__ float bf2f(uint32_t lo16) {
  union { uint32_t u; float f; } x; x.u = lo16 << 16; return x.f;
}

__device__ __forceinline__ void async_load16(const u16* g, u16* l) {
  __builtin_amdgcn_global_load_lds(
      (const __attribute__((address_space(1))) void*)g,
      (__attribute__((address_space(3))) void*)l,
      16, 0, 0);
}

// ---------------- prep_all: sigmoid(beta) + weight converts + x convert ----------------
__global__ __launch_bounds__(256) void prep_all(const float* __restrict__ x,
                                                const float* __restrict__ Wq,
                                                const float* __restrict__ Wfc,
                                                const float* __restrict__ braw,
                                                u16* __restrict__ xb,
                                                u16* __restrict__ wqb,
                                                u16* __restrict__ wfcb,
                                                float* __restrict__ beta) {
  int gid = blockIdx.x * 256 + threadIdx.x;
  if (gid < 1024) beta[gid] = 1.0f / (1.0f + expf(-braw[gid]));
  if (gid < 131072) {
    const int HH = 1024 * 1024;
    int i = gid * 16;
    const float* src = (i < HH) ? (Wq + i) : (Wfc + (i - HH));
    u16* dst = (i < HH) ? (wqb + i) : (wfcb + (i - HH));
#pragma unroll
    for (int c = 0; c < 4; c++) {
      float4 v = *(const float4*)(src + c * 4);
      ushort4 o = {f2bf(v.x), f2bf(v.y), f2bf(v.z), f2bf(v.w)};
      *(ushort4*)(dst + c * 4) = o;
    }
  }
  {
    int i = gid * 8;
    float4 a = *(const float4*)(x + i);
    float4 b = *(const float4*)(x + i + 4);
    ushort4 o0 = {f2bf(a.x), f2bf(a.y), f2bf(a.z), f2bf(a.w)};
    ushort4 o1 = {f2bf(b.x), f2bf(b.y), f2bf(b.z), f2bf(b.w)};
    *(ushort4*)(xb + i) = o0;
    *(ushort4*)(xb + i + 4) = o1;
  }
}

// ---------------- GEMM: C = A (MxK bf16) * B^T (NxK bf16) + bias ----------------
// 128x128 tile, BK=64 (16 K-iters -> half the barrier drains vs BK=32), 4 waves
// (2x2), each wave 64x64 via 4x4 mfma_f32_16x16x32_bf16, two 32-k sub-steps/iter.
// XOR-8 LDS swizzle (key = row&7) keeps ds_read_b128 conflict-free while satisfying
// global_load_lds's wave-uniform-base + lane*16 dest constraint.
// EXPLICIT s_waitcnt(0) before the post-staging barrier: r3 raced without it
// (compiler's drain insertion is code-shape dependent); r4 validated the explicit
// drain pattern through graph-replay revalidation.
template <int RELU, int OUTBF>
__global__ __launch_bounds__(256) void gemm_bt(const u16* __restrict__ A,
                                               const u16* __restrict__ B,
                                               const float* __restrict__ bias,
                                               void* __restrict__ Cout,
                                               int M, int N, int K) {
  __shared__ u16 As[128 * 64];
  __shared__ u16 Bs[128 * 64];

  const int tid  = threadIdx.x;
  const int lane = tid & 63;

  // XCD-aware remap (grid = 1024 = 128 m-tiles x 8 n-tiles; xcd = L % 8):
  // XCD c owns m-tiles [16c,16c+16) x all 8 n-tiles -> ~3 MB L2 working set.
  const int L  = blockIdx.x;
  const int xc = L & 7;
  const int k8 = L >> 3;
  const int tile_n = (k8 & 7) * 128;
  const int tile_m = ((xc << 4) | (k8 >> 3)) * 128;

  const int wm = ((tid >> 7) & 1) * 64;
  const int wn = ((tid >> 6) & 1) * 64;

  // staging: per issue, 256 threads cover 32 rows x 8 chunks(16B). Thread tid:
  // row = tid>>3, dest chunk = tid&7, source global chunk = (tid&7) ^ (row&7).
  const int srow   = tid >> 3;
  const int schunk = (tid & 7) ^ ((tid >> 3) & 7);
  u16* ldsA = &As[((tid >> 6) * 8) * 64];  // wave-uniform: wave w -> rows w*8.. (+32/issue)
  u16* ldsB = &Bs[((tid >> 6) * 8) * 64];

  const u16* gA = A + (size_t)(tile_m + srow) * K + schunk * 8;
  const u16* gB = B + (size_t)(tile_n + srow) * K + schunk * 8;

  f32x4 acc[4][4];
#pragma unroll
  for (int i = 0; i < 4; i++)
#pragma unroll
    for (int j = 0; j < 4; j++) acc[i][j] = (f32x4){0.f, 0.f, 0.f, 0.f};

  const int lrow = lane & 15;
  const int kq   = lane >> 4;

  for (int k0 = 0; k0 < K; k0 += 64) {
    __syncthreads();
#pragma unroll
    for (int i = 0; i < 4; i++) {
      async_load16(gA + (size_t)(i * 32) * K + k0, ldsA + i * 32 * 64);
      async_load16(gB + (size_t)(i * 32) * K + k0, ldsB + i * 32 * 64);
    }
    __builtin_amdgcn_s_waitcnt(0);  // contractual LDS-DMA drain before publish
    __syncthreads();

#pragma unroll
    for (int js = 0; js < 2; js++) {
      // fragment wants global chunk kq+4*js of its row; stored at chunk ^ (row&7);
      // row&7 == lane&7 for all fragment rows (row offsets are multiples of 16).
      const int cc = ((kq + 4 * js) ^ (lane & 7)) << 3;
      bf16x8 a[4], b[4];
#pragma unroll
      for (int i = 0; i < 4; i++)
        a[i] = *(const bf16x8*)&As[(wm + i * 16 + lrow) * 64 + cc];
#pragma unroll
      for (int j = 0; j < 4; j++)
        b[j] = *(const bf16x8*)&Bs[(wn + j * 16 + lrow) * 64 + cc];
#pragma unroll
      for (int i = 0; i < 4; i++)
#pragma unroll
        for (int j = 0; j < 4; j++)
          acc[i][j] = __builtin_amdgcn_mfma_f32_16x16x32_bf16(a[i], b[j], acc[i][j], 0, 0, 0);
    }
  }

  // C/D layout: col = lane&15, row = (lane>>4)*4 + r  [measured m89/m91]
  const int crow = (lane >> 4) << 2;
  const int ccol = lane & 15;
#pragma unroll
  for (int i = 0; i < 4; i++) {
#pragma unroll
    for (int j = 0; j < 4; j++) {
      const int gm = tile_m + wm + i * 16 + crow;
      const int gn = tile_n + wn + j * 16 + ccol;
      const float bv = bias[gn];
#pragma unroll
      for (int r = 0; r < 4; r++) {
        float v = acc[i][j][r] + bv;
        if (RELU) v = fmaxf(v, 0.f);
        if (OUTBF) ((u16*)Cout)[(size_t)(gm + r) * N + gn] = f2bf(v);
        else       ((float*)Cout)[(size_t)(gm + r) * N + gn] = v;
      }
    }
  }
}

// ---------------- scan: m_t = beta*m_{t-1} + q_t over T=2048, channels = B*H = 8192 ----
// q is bf16 [T][8192]. 64 segments of 32 t-steps.
#define NCH 8192
#define SEG 32
#define NSEG 64

// pass1: per-segment carries (fp32 Horner over bf16 q; no double quantization).
__global__ __launch_bounds__(256) void scan_carry(const uint2* __restrict__ qb,
                                                  float* __restrict__ carry,
                                                  const float* __restrict__ beta_arr) {
  int tid = blockIdx.x * 256 + threadIdx.x;  // [0, 64*2048)
  int seg = tid >> 11;
  int cq  = tid & 2047;                      // channel quad
  int h0  = (cq * 4) & 1023;
  float b0 = beta_arr[h0], b1 = beta_arr[h0 + 1], b2 = beta_arr[h0 + 2], b3 = beta_arr[h0 + 3];
  const uint2* p = qb + (size_t)seg * SEG * 2048 + cq;
  float m0 = 0.f, m1 = 0.f, m2 = 0.f, m3 = 0.f;
#pragma unroll 8
  for (int t = 0; t < SEG; t++) {
    uint2 v = p[(size_t)t * 2048];
    m0 = fmaf(b0, m0, bf2f(v.x & 0xffffu));
    m1 = fmaf(b1, m1, bf2f(v.x >> 16));
    m2 = fmaf(b2, m2, bf2f(v.y & 0xffffu));
    m3 = fmaf(b3, m3, bf2f(v.y >> 16));
  }
  *(float4*)&carry[(size_t)seg * NCH + cq * 4] = make_float4(m0, m1, m2, m3);
}

// pass2 (fused fold + rescan): F = Horner-fold of the seg upstream carries with
// ratio beta^32 (2 MB buffer, L2-resident), then rescan 32 q steps from m=F and
// emit bf16 m. seg is uniform per block (8 blocks per segment).
__global__ __launch_bounds__(256) void scan_fuse(const uint2* __restrict__ qb,
                                                 const float4* __restrict__ carry4,
                                                 const float* __restrict__ beta_arr,
                                                 uint2* __restrict__ mb) {
  const int tid = blockIdx.x * 256 + threadIdx.x;  // [0, 64*2048)
  const int seg = tid >> 11;
  const int cq  = tid & 2047;
  const int h0  = (cq * 4) & 1023;
  const float b0 = beta_arr[h0], b1 = beta_arr[h0 + 1];
  const float b2 = beta_arr[h0 + 2], b3 = beta_arr[h0 + 3];
  float s0 = b0, s1 = b1, s2 = b2, s3 = b3;
#pragma unroll
  for (int i = 0; i < 5; i++) { s0 *= s0; s1 *= s1; s2 *= s2; s3 *= s3; }  // beta^32
  float m0 = 0.f, m1 = 0.f, m2 = 0.f, m3 = 0.f;
  const float4* cp = carry4 + cq;
  for (int s = 0; s < seg; s++) {  // uniform per block
    float4 c = cp[(size_t)s * 2048];
    m0 = fmaf(s0, m0, c.x); m1 = fmaf(s1, m1, c.y);
    m2 = fmaf(s2, m2, c.z); m3 = fmaf(s3, m3, c.w);
  }
  const uint2* p = qb + (size_t)seg * SEG * 2048 + cq;
  uint2* o = mb + (size_t)seg * SEG * 2048 + cq;
#pragma unroll 8
  for (int t = 0; t < SEG; t++) {
    uint2 v = p[(size_t)t * 2048];
    m0 = fmaf(b0, m0, bf2f(v.x & 0xffffu));
    m1 = fmaf(b1, m1, bf2f(v.x >> 16));
    m2 = fmaf(b2, m2, bf2f(v.y & 0xffffu));
    m3 = fmaf(b3, m3, bf2f(v.y >> 16));
    uint2 w;
    w.x = (uint32_t)f2bf(m0) | ((uint32_t)f2bf(m1) << 16);
    w.y = (uint32_t)f2bf(m2) | ((uint32_t)f2bf(m3) << 16);
    o[(size_t)t * 2048] = w;
  }
}

extern "C" void kernel_launch(void* const* d_in, const int* in_sizes, int n_in,
                              void* d_out, int out_size, void* d_ws, size_t ws_size,
                              hipStream_t stream) {
  const float* x        = (const float*)d_in[0];
  const float* W_q      = (const float*)d_in[1];
  const float* b_q      = (const float*)d_in[2];
  const float* beta_raw = (const float*)d_in[3];
  const float* W_fc     = (const float*)d_in[4];
  const float* b_fc     = (const float*)d_in[5];

  const int H = 1024;
  const int M = 2048 * 8;              // T*B = 16384 rows
  const size_t MH = (size_t)M * H;     // 16.7M elements

  char* ws = (char*)d_ws;
  u16* x_bf    = (u16*)ws;  ws += MH * 2;                   // 32 MB
  u16* q_bf    = (u16*)ws;  ws += MH * 2;                   // 32 MB
  u16* m_bf    = (u16*)ws;  ws += MH * 2;                   // 32 MB
  u16* wq_bf   = (u16*)ws;  ws += (size_t)H * H * 2;        // 2 MB
  u16* wfc_bf  = (u16*)ws;  ws += (size_t)H * H * 2;        // 2 MB
  float* beta  = (float*)ws; ws += 4096;
  float* carry = (float*)ws; ws += (size_t)NSEG * NCH * 4;  // 2 MB

  prep_all<<<(int)(MH / 8 / 256), 256, 0, stream>>>(x, W_q, W_fc, beta_raw,
                                                    x_bf, wq_bf, wfc_bf, beta);

  gemm_bt<0, 1><<<1024, 256, 0, stream>>>(x_bf, wq_bf, b_q, q_bf, M, H, H);

  scan_carry<<<NSEG * (NCH / 4) / 256, 256, 0, stream>>>((const uint2*)q_bf, carry, beta);
  scan_fuse<<<NSEG * (NCH / 4) / 256, 256, 0, stream>>>((const uint2*)q_bf,
                                                        (const float4*)carry, beta,
                                                        (uint2*)m_bf);

  gemm_bt<1, 0><<<1024, 256, 0, stream>>>(m_bf, wfc_bf, b_fc, d_out, M, H, H);
}